// Round 12
// baseline (599.119 us; speedup 1.0000x reference)
//
#include <hip/hip_runtime.h>

// GaussianSoftmax: out[b,n,m] = softmax_m( exp( exp(-max(||x_n-x_m||^2,0)/sigma) ) )
// X: [8, 4096, 16] fp32, sigma: [1], out: [8, 4096, 4096] fp32 (512 MiB).
// R12 = R11 (203 us kernel: bf16 e in 32KiB LDS, packed f-major Xt, SGPR q,
// sqm precomputed, nontemporal stores) + store/compute overlap:
//  - each block loops over TILES=8 row-tiles (grid exactly 4 blocks/CU,
//    long-lived) so tile t's stores overlap tile t+1's compute;
//  - the per-tile sum-exchange barrier is a raw `s_waitcnt lgkmcnt(0);
//    s_barrier` (inline asm): unlike __syncthreads, it does NOT drain
//    vmcnt, so in-flight stores survive the barrier (m97: compiler drains
//    vmcnt(0) before s_barrier; that drain was the serializer);
//  - lds_e is THREAD-PRIVATE (each thread writes/reads only its own
//    columns; DS ops are in-order per wave) -> needs no barrier at all;
//    only `red` is cross-wave, double-buffered by tile parity.

typedef float v4f __attribute__((ext_vector_type(4)));

constexpr int Bn  = 8;
constexpr int N   = 4096;
constexpr int F   = 16;
constexpr int TN  = 4;        // rows per tile
constexpr int TILES = 8;      // row-tiles per block
constexpr int BLK = 512;      // 8 waves/block; 32 KiB LDS -> 4 blocks/CU
constexpr int WPB = BLK / 64;
constexpr int GROUPS = (N / 4) / BLK;   // 2 float4-column groups per thread

__global__ __launch_bounds__(256)
void pack_kernel(const float* __restrict__ X, float* __restrict__ Xt,
                 float* __restrict__ sqm) {
    const int b = blockIdx.y;
    const int m = blockIdx.x * 256 + threadIdx.x;
    const float4* src = (const float4*)(X + ((size_t)b * N + m) * F);
    const float4 v0 = src[0], v1 = src[1], v2 = src[2], v3 = src[3];
    const float x[F] = {v0.x, v0.y, v0.z, v0.w, v1.x, v1.y, v1.z, v1.w,
                        v2.x, v2.y, v2.z, v2.w, v3.x, v3.y, v3.z, v3.w};
    float* dst = Xt + (size_t)b * F * N + m;
    float s = 0.f;
    #pragma unroll
    for (int f = 0; f < F; ++f) {
        dst[(size_t)f * N] = x[f];              // coalesced dwords
        s = fmaf(x[f], x[f], s);
    }
    sqm[(size_t)b * N + m] = s;                 // ||x_m||^2
}

__device__ __forceinline__ float uni(float x) {  // force SGPR residency
    return __int_as_float(__builtin_amdgcn_readfirstlane(__float_as_int(x)));
}

__device__ __forceinline__ float gse(float d, float base, float nis) {
    float sqd = fmaxf(fmaf(-2.0f, d, base), 0.0f);
    return __expf(__expf(sqd * nis));
}

__device__ __forceinline__ unsigned short f2bf(float x) {   // RNE, no NaN in range
    unsigned int u = __float_as_uint(x);
    unsigned int r = (u + 0x7FFFu + ((u >> 16) & 1u)) >> 16;
    return (unsigned short)r;
}
__device__ __forceinline__ float bf2f(unsigned short h) {
    return __uint_as_float(((unsigned int)h) << 16);
}

// Workgroup barrier WITHOUT the compiler's vmcnt(0) drain: LDS ops drained
// (cross-wave `red` visibility), global stores stay in flight.
__device__ __forceinline__ void barrier_nodrain() {
    asm volatile("s_waitcnt lgkmcnt(0)\n\ts_barrier" ::: "memory");
}

__global__ __launch_bounds__(BLK)
void gs_single(const float* __restrict__ X, const float* __restrict__ Xt,
               const float* __restrict__ sqm, const float* __restrict__ sigma_p,
               float* __restrict__ out) {
    __shared__ unsigned short lds_e[TN][N];   // 32 KiB; THREAD-PRIVATE addresses
    __shared__ float red[2][TN][WPB];         // cross-wave sums, tile-parity dbuf

    const int tid = threadIdx.x;
    const int b   = blockIdx.y;
    const float nis = uni(-1.0f / sigma_p[0]);

    const float4* Xt4  = (const float4*)(Xt + (size_t)b * F * N);
    const float4* sqm4 = (const float4*)(sqm + (size_t)b * N);

    for (int t = 0; t < TILES; ++t) {
        const int n0 = (blockIdx.x * TILES + t) * TN;

        // Query rows: 16 vector loads (full ILP), readfirstlane -> SGPRs.
        const float4* qbase = (const float4*)(X + ((size_t)b * N + n0) * F);
        float q[TN][F];
        float sqn[TN];
        #pragma unroll
        for (int r = 0; r < TN; ++r) {
            const float4 a0 = qbase[r * 4 + 0];
            const float4 a1 = qbase[r * 4 + 1];
            const float4 a2 = qbase[r * 4 + 2];
            const float4 a3 = qbase[r * 4 + 3];
            q[r][ 0] = uni(a0.x); q[r][ 1] = uni(a0.y); q[r][ 2] = uni(a0.z); q[r][ 3] = uni(a0.w);
            q[r][ 4] = uni(a1.x); q[r][ 5] = uni(a1.y); q[r][ 6] = uni(a1.z); q[r][ 7] = uni(a1.w);
            q[r][ 8] = uni(a2.x); q[r][ 9] = uni(a2.y); q[r][10] = uni(a2.z); q[r][11] = uni(a2.w);
            q[r][12] = uni(a3.x); q[r][13] = uni(a3.y); q[r][14] = uni(a3.z); q[r][15] = uni(a3.w);
            float s = 0.f;
            #pragma unroll
            for (int f = 0; f < F; ++f) s = fmaf(q[r][f], q[r][f], s);
            sqn[r] = uni(s);
        }

        float sums[TN] = {0.f, 0.f, 0.f, 0.f};

        #pragma unroll
        for (int g = 0; g < GROUPS; ++g) {
            const int c4 = g * BLK + tid;     // float4-column index

            float4 d[TN];
            #pragma unroll
            for (int r = 0; r < TN; ++r) d[r] = make_float4(0.f, 0.f, 0.f, 0.f);

            #pragma unroll
            for (int fb = 0; fb < F / 4; ++fb) {
                float4 v0 = Xt4[(size_t)(fb * 4 + 0) * (N / 4) + c4];
                float4 v1 = Xt4[(size_t)(fb * 4 + 1) * (N / 4) + c4];
                float4 v2 = Xt4[(size_t)(fb * 4 + 2) * (N / 4) + c4];
                float4 v3 = Xt4[(size_t)(fb * 4 + 3) * (N / 4) + c4];

                #pragma unroll
                for (int k = 0; k < 4; ++k) {
                    const float4 w = (k == 0) ? v0 : (k == 1) ? v1 : (k == 2) ? v2 : v3;
                    #pragma unroll
                    for (int r = 0; r < TN; ++r) {
                        const float qf = q[r][fb * 4 + k];   // SGPR operand
                        d[r].x = fmaf(qf, w.x, d[r].x);
                        d[r].y = fmaf(qf, w.y, d[r].y);
                        d[r].z = fmaf(qf, w.z, d[r].z);
                        d[r].w = fmaf(qf, w.w, d[r].w);
                    }
                }
            }

            const float4 sm = sqm4[c4];       // ||x_m||^2 for these 4 columns

            #pragma unroll
            for (int r = 0; r < TN; ++r) {
                float ex = gse(d[r].x, sqn[r] + sm.x, nis);
                float ey = gse(d[r].y, sqn[r] + sm.y, nis);
                float ez = gse(d[r].z, sqn[r] + sm.z, nis);
                float ew = gse(d[r].w, sqn[r] + sm.w, nis);
                ushort4 pk;
                pk.x = f2bf(ex); pk.y = f2bf(ey); pk.z = f2bf(ez); pk.w = f2bf(ew);
                *(ushort4*)&lds_e[r][4 * c4] = pk;     // own columns only
                sums[r] += (ex + ey) + (ez + ew);
            }
        }

        // Cross-wave sum exchange (the ONLY cross-thread data).
        #pragma unroll
        for (int r = 0; r < TN; ++r) {
            float s = sums[r];
            #pragma unroll
            for (int off = 32; off > 0; off >>= 1) s += __shfl_down(s, off, 64);
            if ((tid & 63) == 0) red[t & 1][r][tid >> 6] = s;
        }
        barrier_nodrain();   // drains LDS only; tile t-1 stores stay in flight

        float inv[TN];
        #pragma unroll
        for (int r = 0; r < TN; ++r) {
            float tt = 0.f;
            #pragma unroll
            for (int w = 0; w < WPB; ++w) tt += red[t & 1][r][w];
            inv[r] = 1.0f / tt;
        }

        // Store phase: unpack own lds_e, scale, nontemporal stores (in flight
        // across the next tile's compute — no vmcnt drain anywhere).
        float* outb = out + ((size_t)b * N + n0) * (size_t)N;
        #pragma unroll
        for (int r = 0; r < TN; ++r) {
            #pragma unroll
            for (int g = 0; g < GROUPS; ++g) {
                const int c4 = g * BLK + tid;
                ushort4 pk = *(const ushort4*)&lds_e[r][4 * c4];
                v4f v;
                v.x = bf2f(pk.x) * inv[r];
                v.y = bf2f(pk.y) * inv[r];
                v.z = bf2f(pk.z) * inv[r];
                v.w = bf2f(pk.w) * inv[r];
                __builtin_nontemporal_store(v, (v4f*)(outb + (size_t)r * N) + c4);
            }
        }
    }
}

extern "C" void kernel_launch(void* const* d_in, const int* in_sizes, int n_in,
                              void* d_out, int out_size, void* d_ws, size_t ws_size,
                              hipStream_t stream) {
    const float* X     = (const float*)d_in[0];
    const float* sigma = (const float*)d_in[1];
    float* out         = (float*)d_out;
    float* Xt          = (float*)d_ws;                        // 2 MiB
    float* sqm         = (float*)d_ws + (size_t)Bn * F * N;   // +128 KiB

    pack_kernel<<<dim3(N / 256, Bn), 256, 0, stream>>>(X, Xt, sqm);
    gs_single<<<dim3(N / (TN * TILES), Bn), BLK, 0, stream>>>(X, Xt, sqm, sigma, out);
}